// Round 5
// baseline (519.707 us; speedup 1.0000x reference)
//
#include <hip/hip_runtime.h>
#include <hip/hip_cooperative_groups.h>

namespace cg = cooperative_groups;

#define NB 128
#define NP 8732
#define NO 32
#define NC 21
#define NCH 4
#define CPB 2304           // priors per chunk; 3*2304 + 1820 = 8732; tails {28} keep cnt*21 % 4 == 0
#define NBLK (NB * NCH)    // 512 blocks = 2 per CU (cooperative co-residency)

// ---------------- workspace layout ----------------
// [0, 32768)        : unsigned long long packed[NB*NO]
// [32768, 33280)    : int npos[NB]
// [33280, 36352)    : double accb[NB][3]  (0=pos_conf, 1=loc, 2=hard_neg)
// [36352, +NB*NP*4) : int code[NB*NP]     (obj | matched-flag<<8)
// [..., +NB*NP*4)   : float confneg[NB*NP]

__global__ __launch_bounds__(256, 2) void k_fused(
    const float* __restrict__ plocs, const float* __restrict__ scores,
    const float* __restrict__ boxes, const int* __restrict__ labels,
    const float* __restrict__ priors,
    unsigned long long* packed, int* npos, double* accb,
    int* code, float* confneg, float* out, int* zbase) {
    cg::grid_group grid = cg::this_grid();
    const int bid = blockIdx.x, tid = threadIdx.x;
    const int lane = tid & 63, wid = tid >> 6;

    __shared__ union {
        struct { float4 box[NO]; float4 pri[CPB]; } a;  // 512 + 36864 B
        float srow[256 * NC];                            // 21504 B
    } sm;
    __shared__ float sw0[4], sw1[4];
    __shared__ int swc[4], sig[4], ssum;
    __shared__ double sdg[4];
    __shared__ unsigned long long sforce[NO];
    __shared__ double sfin[4][4];

    const int b = bid >> 2;   // image
    const int c = bid & 3;    // prior chunk
    const int pbeg = c * CPB;
    const int n = min(CPB, NP - pbeg);  // 2304 or 1820

    // ---------- phase 0: zero packed/npos/accb (ws is poisoned 0xAA) ----------
    { int i = bid * 256 + tid; if (i < 36352 / 4) zbase[i] = 0; }
    grid.sync();

    // ---------- phase A: matching (each IoU computed ONCE, both directions) ----------
    {
        if (tid < NO) sm.a.box[tid] = ((const float4*)boxes)[b * NO + tid];
        for (int i = tid; i < n; i += 256) {
            float4 pr = ((const float4*)priors)[pbeg + i];
            sm.a.pri[i] = make_float4(pr.x - pr.z * 0.5f, pr.y - pr.w * 0.5f,
                                      pr.x + pr.z * 0.5f, pr.y + pr.w * 0.5f);
        }
        __syncthreads();

        float x1[9], y1[9], x2[9], y2[9], ar[9], bv[9];
        int bo[9];
#pragma unroll
        for (int j = 0; j < 9; ++j) {
            int i = tid + j * 256;
            int ic = i < n ? i : 0;  // clamp LDS read; update masked below
            float4 pr = sm.a.pri[ic];
            x1[j] = pr.x; y1[j] = pr.y; x2[j] = pr.z; y2[j] = pr.w;
            ar[j] = (pr.z - pr.x) * (pr.w - pr.y);
            bv[j] = -1.0f; bo[j] = 0;
        }

        for (int o = 0; o < NO; ++o) {
            float4 bx = sm.a.box[o];  // LDS broadcast
            float a1 = (bx.z - bx.x) * (bx.w - bx.y);
            unsigned long long pk = 0ull;
#pragma unroll
            for (int j = 0; j < 9; ++j) {
                int i = tid + j * 256;
                float lx = fmaxf(bx.x, x1[j]), ly = fmaxf(bx.y, y1[j]);
                float hx = fminf(bx.z, x2[j]), hy = fminf(bx.w, y2[j]);
                float iw = fmaxf(hx - lx, 0.0f), ih = fmaxf(hy - ly, 0.0f);
                float inter = iw * ih;
                float iou = inter / (a1 + ar[j] - inter);
                if (i < n) {
                    if (iou > bv[j]) { bv[j] = iou; bo[j] = o; }  // first max wins
                    // larger iou wins; tie -> smaller p (matches jnp.argmax)
                    unsigned long long key =
                        ((unsigned long long)__float_as_uint(iou) << 32) |
                        (unsigned long long)(0xFFFFFFFFu - (unsigned)(pbeg + i));
                    if (key > pk) pk = key;
                }
            }
            for (int s = 32; s > 0; s >>= 1) {
                unsigned long long t = __shfl_xor(pk, s, 64);
                if (t > pk) pk = t;
            }
            if (lane == 0) atomicMax(&packed[b * NO + o], pk);
        }
#pragma unroll
        for (int j = 0; j < 9; ++j) {
            int i = tid + j * 256;
            if (i < n)
                code[(size_t)b * NP + pbeg + i] = bo[j] | (bv[j] >= 0.5f ? 256 : 0);
        }
    }
    grid.sync();

    // ---------- phase B: forced matches (last o wins, single-thread ordered stores) ----------
    if (bid < NB) {
        if (tid < NO) sforce[tid] = packed[bid * NO + tid];
        __syncthreads();
        if (tid == 0) {
#pragma unroll
            for (int o = 0; o < NO; ++o) {
                unsigned p = 0xFFFFFFFFu - (unsigned)(sforce[o] & 0xFFFFFFFFull);
                code[(size_t)bid * NP + p] = o | 256;
            }
        }
    }
    grid.sync();

    // ---------- phase C: CE + loc loss, confneg ----------
    {
        float posconf = 0.0f, locpart = 0.0f;
        int isp = 0;
        for (int t0 = 0; t0 < n; t0 += 256) {
            int cnt = min(256, n - t0);       // 256 or 28; cnt*21 % 4 == 0
            int nf4 = cnt * NC / 4;
            const float4* src4 = (const float4*)(scores + ((size_t)b * NP + pbeg + t0) * NC);
            __syncthreads();                  // protect srow reuse
            for (int i = tid; i < nf4; i += 256) ((float4*)sm.srow)[i] = src4[i];
            __syncthreads();
            if (tid < cnt) {
                int p = pbeg + t0 + tid;
                int cd = code[(size_t)b * NP + p];
                int obj = cd & 255;
                int lbl = (cd & 256) ? labels[b * NO + obj] : 0;
                const float* s = sm.srow + tid * NC;  // stride 21: conflict-free
                float m = s[0];
#pragma unroll
                for (int cc = 1; cc < NC; ++cc) m = fmaxf(m, s[cc]);
                float sum = 0.0f;
#pragma unroll
                for (int cc = 0; cc < NC; ++cc) sum += __expf(s[cc] - m);
                float conf = m + __logf(sum) - s[lbl];
                if (lbl != 0) {
                    isp++;
                    posconf += conf;
                    float4 bx = ((const float4*)boxes)[b * NO + obj];
                    float4 pr = ((const float4*)priors)[p];
                    float cx = (bx.x + bx.z) * 0.5f, cy = (bx.y + bx.w) * 0.5f;
                    float w = bx.z - bx.x, h = bx.w - bx.y;
                    float gx = (cx - pr.x) / (pr.z * 0.1f);
                    float gy = (cy - pr.y) / (pr.w * 0.1f);
                    float gw = __logf(w / pr.z) * 5.0f;
                    float gh = __logf(h / pr.w) * 5.0f;
                    float4 pl = ((const float4*)plocs)[(size_t)b * NP + p];
                    locpart += fabsf(pl.x - gx) + fabsf(pl.y - gy) +
                               fabsf(pl.z - gw) + fabsf(pl.w - gh);
                    confneg[(size_t)b * NP + p] = 0.0f;
                } else {
                    confneg[(size_t)b * NP + p] = conf;
                }
            }
        }
        for (int s = 32; s > 0; s >>= 1) {
            posconf += __shfl_xor(posconf, s, 64);
            locpart += __shfl_xor(locpart, s, 64);
            isp     += __shfl_xor(isp, s, 64);
        }
        if (lane == 0) { sw0[wid] = posconf; sw1[wid] = locpart; swc[wid] = isp; }
        __syncthreads();
        if (tid == 0) {
            atomicAdd(&npos[b], swc[0] + swc[1] + swc[2] + swc[3]);
            atomicAdd(&accb[b * 3 + 0], (double)(sw0[0] + sw0[1] + sw0[2] + sw0[3]));
            atomicAdd(&accb[b * 3 + 1], (double)(sw1[0] + sw1[1] + sw1[2] + sw1[3]));
        }
    }
    grid.sync();

    // ---------- phase D: exact top-k hard-negative sum (bit bisection) ----------
    if (bid < NB) {
        const float* src = confneg + (size_t)bid * NP;
        float val[35];
#pragma unroll
        for (int j = 0; j < 35; ++j) {
            int i = tid + j * 256;
            val[j] = (i < NP) ? src[i] : 0.0f;  // 0 never counts (cand > 0)
        }
        int k = npos[bid] * 3;
        if (k > NP) k = NP;
        if (k > 0) {  // block-uniform
            unsigned T = 0;
            for (int bit = 30; bit >= 0; --bit) {
                unsigned cand = T | (1u << bit);
                int cnt = 0;
#pragma unroll
                for (int j = 0; j < 35; ++j)
                    cnt += (__float_as_uint(val[j]) >= cand) ? 1 : 0;
                for (int s = 32; s > 0; s >>= 1) cnt += __shfl_xor(cnt, s, 64);
                if (lane == 0) sig[wid] = cnt;
                __syncthreads();
                if (tid == 0) ssum = sig[0] + sig[1] + sig[2] + sig[3];
                __syncthreads();
                if (ssum >= k) T = cand;
            }
            int cgt = 0;
            double sgt = 0.0;
#pragma unroll
            for (int j = 0; j < 35; ++j) {
                unsigned u = __float_as_uint(val[j]);
                if (u > T) { cgt++; sgt += (double)val[j]; }
            }
            for (int s = 32; s > 0; s >>= 1) {
                cgt += __shfl_xor(cgt, s, 64);
                sgt += __shfl_xor(sgt, s, 64);
            }
            if (lane == 0) { sig[wid] = cgt; sdg[wid] = sgt; }
            __syncthreads();
            if (tid == 0) {
                int cg = sig[0] + sig[1] + sig[2] + sig[3];
                double sg = sdg[0] + sdg[1] + sdg[2] + sdg[3];
                accb[bid * 3 + 2] = sg + (double)(k - cg) * (double)__uint_as_float(T);
            }
        }
    }
    grid.sync();

    // ---------- phase E: final scalar ----------
    if (bid == 0) {
        double pc = 0, lc = 0, hn = 0, nn = 0;
        if (tid < NB) {
            pc = accb[tid * 3 + 0];
            lc = accb[tid * 3 + 1];
            hn = accb[tid * 3 + 2];
            nn = (double)npos[tid];
        }
        for (int s = 32; s > 0; s >>= 1) {
            pc += __shfl_xor(pc, s, 64);
            lc += __shfl_xor(lc, s, 64);
            hn += __shfl_xor(hn, s, 64);
            nn += __shfl_xor(nn, s, 64);
        }
        if (lane == 0) { sfin[0][wid] = pc; sfin[1][wid] = lc; sfin[2][wid] = hn; sfin[3][wid] = nn; }
        __syncthreads();
        if (tid == 0) {
            double P  = sfin[0][0] + sfin[0][1] + sfin[0][2] + sfin[0][3];
            double L  = sfin[1][0] + sfin[1][1] + sfin[1][2] + sfin[1][3];
            double H  = sfin[2][0] + sfin[2][1] + sfin[2][2] + sfin[2][3];
            double NT = sfin[3][0] + sfin[3][1] + sfin[3][2] + sfin[3][3];
            out[0] = (float)((H + P) / NT + L / (NT * 4.0));
        }
    }
}

extern "C" void kernel_launch(void* const* d_in, const int* in_sizes, int n_in,
                              void* d_out, int out_size, void* d_ws, size_t ws_size,
                              hipStream_t stream) {
    const float* plocs  = (const float*)d_in[0];
    const float* scores = (const float*)d_in[1];
    const float* boxes  = (const float*)d_in[2];
    const int*   labels = (const int*)d_in[3];
    const float* priors = (const float*)d_in[4];
    float* out = (float*)d_out;

    char* ws = (char*)d_ws;
    unsigned long long* packed = (unsigned long long*)ws;
    int*    npos    = (int*)(ws + 32768);
    double* accb    = (double*)(ws + 33280);
    int*    code    = (int*)(ws + 36352);
    float*  confneg = (float*)(ws + 36352 + (size_t)NB * NP * 4);
    int*    zbase   = (int*)ws;

    void* args[] = {
        (void*)&plocs, (void*)&scores, (void*)&boxes, (void*)&labels, (void*)&priors,
        (void*)&packed, (void*)&npos, (void*)&accb, (void*)&code, (void*)&confneg,
        (void*)&out, (void*)&zbase
    };
    hipLaunchCooperativeKernel((const void*)k_fused, dim3(NBLK), dim3(256),
                               args, 0, stream);
}

// Round 6
// 312.254 us; speedup vs baseline: 1.6644x; 1.6644x over previous
//
#include <hip/hip_runtime.h>
#include <hip/hip_bf16.h>

#define NB 128
#define NP 8732
#define NO 32
#define NC 21
#define CPB 2183   // NP/4 exactly: 4*2183 = 8732

// ---------------- workspace layout ----------------
// [0, 32768)      : unsigned long long packed[NB*NO]  (plain stores from k_obj)
// [32768, 33280)  : int npos[NB]
// [33280, 36352)  : double accb[NB][3]  (0=pos_conf, 1=loc, 2=hard_neg)
// [36352, 36356)  : int flag (last-block ticket)
// [36608, ...)    : float confneg[NB*NP]

// Per-object argmax over all priors. One block per image, 8 waves x 4 objects.
// Running max keys live in registers across chunks -> plain stores, no atomics,
// no zero-init of packed required. Also zeroes npos/accb/flag for later kernels.
__global__ __launch_bounds__(512) void k_obj(const float* __restrict__ boxes,
                                             const float* __restrict__ priors,
                                             unsigned long long* __restrict__ packed,
                                             int* __restrict__ npos,
                                             double* __restrict__ accb,
                                             int* __restrict__ flag) {
    __shared__ float4 spri[CPB];  // 34928 B
    __shared__ float4 sbox[NO];
    const int b = blockIdx.x, tid = threadIdx.x;
    const int lane = tid & 63, wid = tid >> 6;  // 8 waves

    if (tid == 0) npos[b] = 0;
    if (tid >= 1 && tid <= 3) accb[b * 3 + (tid - 1)] = 0.0;
    if (b == 0 && tid == 4) *flag = 0;
    if (tid < NO) sbox[tid] = ((const float4*)boxes)[b * NO + tid];

    unsigned long long key[4] = {0ull, 0ull, 0ull, 0ull};

    for (int ch = 0; ch < 4; ++ch) {
        const int pbeg = ch * CPB;
        __syncthreads();  // protects spri reuse (and sbox on first iter)
        for (int i = tid; i < CPB; i += 512) {
            float4 pr = ((const float4*)priors)[pbeg + i];
            spri[i] = make_float4(pr.x - pr.z * 0.5f, pr.y - pr.w * 0.5f,
                                  pr.x + pr.z * 0.5f, pr.y + pr.w * 0.5f);
        }
        __syncthreads();
#pragma unroll
        for (int oo = 0; oo < 4; ++oo) {
            const int o = wid * 4 + oo;
            float4 bx = sbox[o];
            float a1 = (bx.z - bx.x) * (bx.w - bx.y);
            unsigned long long pk = key[oo];
            for (int i = lane; i < CPB; i += 64) {
                float4 pr = spri[i];
                float lx = fmaxf(bx.x, pr.x), ly = fmaxf(bx.y, pr.y);
                float hx = fminf(bx.z, pr.z), hy = fminf(bx.w, pr.w);
                float iw = fmaxf(hx - lx, 0.0f), ih = fmaxf(hy - ly, 0.0f);
                float inter = iw * ih;
                float pa = (pr.z - pr.x) * (pr.w - pr.y);
                float iou = inter / (a1 + pa - inter);
                // larger iou wins; tie -> smaller p (matches jnp.argmax)
                unsigned long long k2 =
                    ((unsigned long long)__float_as_uint(iou) << 32) |
                    (unsigned long long)(0xFFFFFFFFu - (unsigned)(pbeg + i));
                if (k2 > pk) pk = k2;
            }
            key[oo] = pk;
        }
    }
#pragma unroll
    for (int oo = 0; oo < 4; ++oo) {
        unsigned long long pk = key[oo];
        for (int s = 32; s > 0; s >>= 1) {
            unsigned long long t = __shfl_xor(pk, s, 64);
            if (t > pk) pk = t;
        }
        if (lane == 0) packed[b * NO + wid * 4 + oo] = pk;
    }
}

// Per-prior: inline best-object IoU (LDS broadcasts), forced-match override from
// packed, CE via LDS-staged scores, loc loss; per-image atomics (128-way spread).
__global__ __launch_bounds__(256) void k_loss(const float* __restrict__ plocs,
                                              const float* __restrict__ scores,
                                              const float* __restrict__ boxes,
                                              const int* __restrict__ labels,
                                              const float* __restrict__ priors,
                                              const unsigned long long* __restrict__ packed,
                                              float* __restrict__ confneg,
                                              int* __restrict__ npos,
                                              double* __restrict__ accb) {
    __shared__ float srow[256 * NC];  // 21504 B
    __shared__ float4 sbox[NO];
    __shared__ int sfp[NO];   // forced prior index per object
    __shared__ int slab[NO];
    const int b = blockIdx.y, tid = threadIdx.x;
    const int p0 = blockIdx.x * 256;
    const int cnt = min(256, NP - p0);  // 256 or 28; cnt*21 % 4 == 0

    if (tid < NO) {
        sbox[tid] = ((const float4*)boxes)[b * NO + tid];
        slab[tid] = labels[b * NO + tid];
        unsigned long long pk = packed[b * NO + tid];
        sfp[tid] = (int)(0xFFFFFFFFu - (unsigned)(pk & 0xFFFFFFFFull));
    }
    const int nf4 = cnt * NC / 4;
    const float4* src4 = (const float4*)(scores + ((size_t)b * NP + p0) * NC);
    for (int i = tid; i < nf4; i += 256) ((float4*)srow)[i] = src4[i];
    __syncthreads();

    float posconf = 0.0f, locpart = 0.0f;
    int isp = 0;

    if (tid < cnt) {
        const int p = p0 + tid;
        float4 pr = ((const float4*)priors)[p];  // cxcy
        float px1 = pr.x - pr.z * 0.5f, py1 = pr.y - pr.w * 0.5f;
        float px2 = pr.x + pr.z * 0.5f, py2 = pr.y + pr.w * 0.5f;
        float pa = (px2 - px1) * (py2 - py1);

        float bestv = -1.0f;
        int besto = 0;
#pragma unroll
        for (int o = 0; o < NO; ++o) {
            float4 bx = sbox[o];  // LDS broadcast (same addr all lanes)
            float a1 = (bx.z - bx.x) * (bx.w - bx.y);
            float lx = fmaxf(bx.x, px1), ly = fmaxf(bx.y, py1);
            float hx = fminf(bx.z, px2), hy = fminf(bx.w, py2);
            float iw = fmaxf(hx - lx, 0.0f), ih = fmaxf(hy - ly, 0.0f);
            float inter = iw * ih;
            float iou = inter / (a1 + pa - inter);
            if (iou > bestv) { bestv = iou; besto = o; }  // first max wins
        }
        int ovr = -1;
#pragma unroll
        for (int o = 0; o < NO; ++o)
            if (sfp[o] == p) ovr = o;  // ascending: last o wins (numpy scatter)

        int obj, matched;
        if (ovr >= 0) { obj = ovr; matched = 1; }
        else          { obj = besto; matched = (bestv >= 0.5f) ? 1 : 0; }
        int lbl = matched ? slab[obj] : 0;

        const float* s = srow + tid * NC;  // stride 21: conflict-free
        float m = s[0];
#pragma unroll
        for (int c = 1; c < NC; ++c) m = fmaxf(m, s[c]);
        float sum = 0.0f;
#pragma unroll
        for (int c = 0; c < NC; ++c) sum += __expf(s[c] - m);
        float conf = m + __logf(sum) - s[lbl];

        if (lbl != 0) {
            isp = 1;
            posconf = conf;
            float4 bx = sbox[obj];
            float cx = (bx.x + bx.z) * 0.5f, cy = (bx.y + bx.w) * 0.5f;
            float w = bx.z - bx.x, h = bx.w - bx.y;
            float gx = (cx - pr.x) / (pr.z * 0.1f);
            float gy = (cy - pr.y) / (pr.w * 0.1f);
            float gw = __logf(w / pr.z) * 5.0f;
            float gh = __logf(h / pr.w) * 5.0f;
            float4 pl = ((const float4*)plocs)[(size_t)b * NP + p];
            locpart = fabsf(pl.x - gx) + fabsf(pl.y - gy) +
                      fabsf(pl.z - gw) + fabsf(pl.w - gh);
        }
        confneg[(size_t)b * NP + p] = isp ? 0.0f : conf;
    }

    for (int s = 32; s > 0; s >>= 1) {
        posconf += __shfl_xor(posconf, s, 64);
        locpart += __shfl_xor(locpart, s, 64);
        isp     += __shfl_xor(isp, s, 64);
    }
    __shared__ float w0[4], w1[4];
    __shared__ int wc[4];
    int wid = tid >> 6, lane = tid & 63;
    if (lane == 0) { w0[wid] = posconf; w1[wid] = locpart; wc[wid] = isp; }
    __syncthreads();
    if (tid == 0) {
        atomicAdd(&npos[b], wc[0] + wc[1] + wc[2] + wc[3]);
        atomicAdd(&accb[b * 3 + 0], (double)(w0[0] + w0[1] + w0[2] + w0[3]));
        atomicAdd(&accb[b * 3 + 1], (double)(w1[0] + w1[1] + w1[2] + w1[3]));
    }
}

// Exact top-k hard-negative sum (bit bisection, register-resident row) + last-block final.
__global__ __launch_bounds__(1024) void k_topk_final(const float* __restrict__ confneg,
                                                     const int* __restrict__ npos,
                                                     double* __restrict__ accb,
                                                     int* __restrict__ flag,
                                                     float* __restrict__ out) {
    __shared__ int   si[16];
    __shared__ double sd[16];
    __shared__ int   sbcast, slast;
    const int tid = threadIdx.x, b = blockIdx.x;
    const int lane = tid & 63, wid = tid >> 6;

    const float* src = confneg + (size_t)b * NP;
    float val[9];
#pragma unroll
    for (int j = 0; j < 9; ++j) {
        int i = tid + j * 1024;
        val[j] = (i < NP) ? src[i] : 0.0f;  // 0 never counts (cand > 0)
    }
    int k = npos[b] * 3;
    if (k > NP) k = NP;

    if (k > 0) {  // block-uniform
        unsigned T = 0;
        for (int bit = 30; bit >= 0; --bit) {
            unsigned cand = T | (1u << bit);
            int cnt = 0;
#pragma unroll
            for (int j = 0; j < 9; ++j)
                cnt += (__float_as_uint(val[j]) >= cand) ? 1 : 0;
            for (int s = 32; s > 0; s >>= 1) cnt += __shfl_xor(cnt, s, 64);
            if (lane == 0) si[wid] = cnt;
            __syncthreads();
            if (tid == 0) {
                int t = 0;
                for (int w = 0; w < 16; ++w) t += si[w];
                sbcast = t;
            }
            __syncthreads();
            if (sbcast >= k) T = cand;
        }
        int cgt = 0;
        double sgt = 0.0;
#pragma unroll
        for (int j = 0; j < 9; ++j) {
            unsigned u = __float_as_uint(val[j]);
            if (u > T) { cgt++; sgt += (double)val[j]; }
        }
        for (int s = 32; s > 0; s >>= 1) {
            cgt += __shfl_xor(cgt, s, 64);
            sgt += __shfl_xor(sgt, s, 64);
        }
        if (lane == 0) { si[wid] = cgt; sd[wid] = sgt; }
        __syncthreads();
        if (tid == 0) {
            int cg = 0; double sg = 0.0;
            for (int w = 0; w < 16; ++w) { cg += si[w]; sg += sd[w]; }
            accb[b * 3 + 2] = sg + (double)(k - cg) * (double)__uint_as_float(T);
        }
    }
    // accb[b*3+2] stays 0 (zeroed by k_obj) when k == 0.

    // last-block ticket
    __threadfence();
    if (tid == 0) slast = (atomicAdd(flag, 1) == NB - 1) ? 1 : 0;
    __syncthreads();
    if (slast) {
        __threadfence();
        double pc = 0, lc = 0, hn = 0, nn = 0;
        if (tid < NB) {
            pc = accb[tid * 3 + 0];
            lc = accb[tid * 3 + 1];
            hn = accb[tid * 3 + 2];
            nn = (double)npos[tid];
        }
        if (tid < 128) {
            for (int s = 32; s > 0; s >>= 1) {
                pc += __shfl_xor(pc, s, 64);
                lc += __shfl_xor(lc, s, 64);
                hn += __shfl_xor(hn, s, 64);
                nn += __shfl_xor(nn, s, 64);
            }
            if (lane == 0) { sd[wid * 4 + 0] = pc; sd[wid * 4 + 1] = lc;
                             sd[wid * 4 + 2] = hn; sd[wid * 4 + 3] = nn; }
        }
        __syncthreads();
        if (tid == 0) {
            double P  = sd[0] + sd[4];
            double L  = sd[1] + sd[5];
            double H  = sd[2] + sd[6];
            double NT = sd[3] + sd[7];
            out[0] = (float)((H + P) / NT + L / (NT * 4.0));
        }
    }
}

extern "C" void kernel_launch(void* const* d_in, const int* in_sizes, int n_in,
                              void* d_out, int out_size, void* d_ws, size_t ws_size,
                              hipStream_t stream) {
    const float* plocs  = (const float*)d_in[0];
    const float* scores = (const float*)d_in[1];
    const float* boxes  = (const float*)d_in[2];
    const int*   labels = (const int*)d_in[3];
    const float* priors = (const float*)d_in[4];
    float* out = (float*)d_out;

    char* ws = (char*)d_ws;
    unsigned long long* packed = (unsigned long long*)ws;
    int*    npos    = (int*)(ws + 32768);
    double* accb    = (double*)(ws + 33280);
    int*    flag    = (int*)(ws + 36352);
    float*  confneg = (float*)(ws + 36608);

    hipLaunchKernelGGL(k_obj, dim3(NB), dim3(512), 0, stream,
                       boxes, priors, packed, npos, accb, flag);
    hipLaunchKernelGGL(k_loss, dim3((NP + 255) / 256, NB), dim3(256), 0, stream,
                       plocs, scores, boxes, labels, priors, packed, confneg, npos, accb);
    hipLaunchKernelGGL(k_topk_final, dim3(NB), dim3(1024), 0, stream,
                       confneg, npos, accb, flag, out);
}

// Round 7
// 268.529 us; speedup vs baseline: 1.9354x; 1.1628x over previous
//
#include <hip/hip_runtime.h>
#include <hip/hip_bf16.h>

#define NB 128
#define NP 8732
#define NO 32
#define NC 21
#define NCH 8
#define CH 1152    // priors per chunk; 7*1152 + 668 = 8732

// ---------------- workspace layout ----------------
// [0, 262144)       : unsigned long long packed2[NB][NO][NCH]  (plain stores, no init needed)
// [262144, 262656)  : int npos[NB]
// [262656, 265728)  : double accb[NB][3]  (0=pos_conf, 1=loc, 2=hard_neg)
// [265728, 265732)  : int flag (last-block ticket)
// [265984, ...)     : float confneg[NB*NP]

// Per-object argmax over priors, chunked: 8 chunks x 128 images = 1024 blocks.
// 4 waves x 8 objects per wave; per-(object,chunk) key -> plain store to packed2.
// Chunk-0 blocks also zero npos/accb/flag (consumed by later kernels, stream-ordered).
__global__ __launch_bounds__(256) void k_obj(const float* __restrict__ boxes,
                                             const float* __restrict__ priors,
                                             unsigned long long* __restrict__ packed2,
                                             int* __restrict__ npos,
                                             double* __restrict__ accb,
                                             int* __restrict__ flag) {
    __shared__ float4 spri[CH];   // 18432 B
    __shared__ float4 sbox[NO];
    const int ch = blockIdx.x, b = blockIdx.y, tid = threadIdx.x;
    const int lane = tid & 63, wid = tid >> 6;  // 4 waves
    const int pbeg = ch * CH;
    const int n = min(CH, NP - pbeg);  // 1152 or 668

    if (ch == 0) {
        if (tid == 0) npos[b] = 0;
        if (tid >= 1 && tid <= 3) accb[b * 3 + (tid - 1)] = 0.0;
        if (b == 0 && tid == 4) *flag = 0;
    }
    if (tid < NO) sbox[tid] = ((const float4*)boxes)[b * NO + tid];
    for (int i = tid; i < n; i += 256) {
        float4 pr = ((const float4*)priors)[pbeg + i];
        spri[i] = make_float4(pr.x - pr.z * 0.5f, pr.y - pr.w * 0.5f,
                              pr.x + pr.z * 0.5f, pr.y + pr.w * 0.5f);
    }
    __syncthreads();

#pragma unroll
    for (int oo = 0; oo < 8; ++oo) {
        const int o = wid * 8 + oo;
        float4 bx = sbox[o];
        float a1 = (bx.z - bx.x) * (bx.w - bx.y);
        unsigned long long pk = 0ull;
        for (int i = lane; i < n; i += 64) {
            float4 pr = spri[i];
            float lx = fmaxf(bx.x, pr.x), ly = fmaxf(bx.y, pr.y);
            float hx = fminf(bx.z, pr.z), hy = fminf(bx.w, pr.w);
            float iw = fmaxf(hx - lx, 0.0f), ih = fmaxf(hy - ly, 0.0f);
            float inter = iw * ih;
            float pa = (pr.z - pr.x) * (pr.w - pr.y);
            float iou = inter / (a1 + pa - inter);
            // larger iou wins; tie -> smaller p (matches jnp.argmax)
            unsigned long long k2 =
                ((unsigned long long)__float_as_uint(iou) << 32) |
                (unsigned long long)(0xFFFFFFFFu - (unsigned)(pbeg + i));
            if (k2 > pk) pk = k2;
        }
        for (int s = 32; s > 0; s >>= 1) {
            unsigned long long t = __shfl_xor(pk, s, 64);
            if (t > pk) pk = t;
        }
        if (lane == 0) packed2[(b * NO + o) * NCH + ch] = pk;
    }
}

// Per-prior: inline best-object IoU (LDS broadcasts), forced-match override from
// packed2 (8-way shuffle reduce at block start), CE via LDS-staged scores, loc loss.
__global__ __launch_bounds__(256) void k_loss(const float* __restrict__ plocs,
                                              const float* __restrict__ scores,
                                              const float* __restrict__ boxes,
                                              const int* __restrict__ labels,
                                              const float* __restrict__ priors,
                                              const unsigned long long* __restrict__ packed2,
                                              float* __restrict__ confneg,
                                              int* __restrict__ npos,
                                              double* __restrict__ accb) {
    __shared__ float srow[256 * NC];  // 21504 B
    __shared__ float4 sbox[NO];
    __shared__ int sfp[NO];   // forced prior index per object
    __shared__ int slab[NO];
    const int b = blockIdx.y, tid = threadIdx.x;
    const int p0 = blockIdx.x * 256;
    const int cnt = min(256, NP - p0);  // 256 or 28; cnt*21 % 4 == 0

    // reduce per-object keys over the 8 chunks: tid = o*8 + ch (o = tid>>3)
    {
        unsigned long long key = packed2[b * (NO * NCH) + tid];
#pragma unroll
        for (int s = 1; s < 8; s <<= 1) {
            unsigned long long t = __shfl_xor(key, s, 64);
            if (t > key) key = t;
        }
        if ((tid & 7) == 0)
            sfp[tid >> 3] = (int)(0xFFFFFFFFu - (unsigned)(key & 0xFFFFFFFFull));
    }
    if (tid < NO) {
        sbox[tid] = ((const float4*)boxes)[b * NO + tid];
        slab[tid] = labels[b * NO + tid];
    }
    const int nf4 = cnt * NC / 4;
    const float4* src4 = (const float4*)(scores + ((size_t)b * NP + p0) * NC);
    for (int i = tid; i < nf4; i += 256) ((float4*)srow)[i] = src4[i];
    __syncthreads();

    float posconf = 0.0f, locpart = 0.0f;
    int isp = 0;

    if (tid < cnt) {
        const int p = p0 + tid;
        float4 pr = ((const float4*)priors)[p];  // cxcy
        float px1 = pr.x - pr.z * 0.5f, py1 = pr.y - pr.w * 0.5f;
        float px2 = pr.x + pr.z * 0.5f, py2 = pr.y + pr.w * 0.5f;
        float pa = (px2 - px1) * (py2 - py1);

        float bestv = -1.0f;
        int besto = 0;
#pragma unroll
        for (int o = 0; o < NO; ++o) {
            float4 bx = sbox[o];  // LDS broadcast (same addr all lanes)
            float a1 = (bx.z - bx.x) * (bx.w - bx.y);
            float lx = fmaxf(bx.x, px1), ly = fmaxf(bx.y, py1);
            float hx = fminf(bx.z, px2), hy = fminf(bx.w, py2);
            float iw = fmaxf(hx - lx, 0.0f), ih = fmaxf(hy - ly, 0.0f);
            float inter = iw * ih;
            float iou = inter / (a1 + pa - inter);
            if (iou > bestv) { bestv = iou; besto = o; }  // first max wins
        }
        int ovr = -1;
#pragma unroll
        for (int o = 0; o < NO; ++o)
            if (sfp[o] == p) ovr = o;  // ascending: last o wins (numpy scatter)

        int obj, matched;
        if (ovr >= 0) { obj = ovr; matched = 1; }
        else          { obj = besto; matched = (bestv >= 0.5f) ? 1 : 0; }
        int lbl = matched ? slab[obj] : 0;

        const float* s = srow + tid * NC;  // stride 21: conflict-free
        float m = s[0];
#pragma unroll
        for (int c = 1; c < NC; ++c) m = fmaxf(m, s[c]);
        float sum = 0.0f;
#pragma unroll
        for (int c = 0; c < NC; ++c) sum += __expf(s[c] - m);
        float conf = m + __logf(sum) - s[lbl];

        if (lbl != 0) {
            isp = 1;
            posconf = conf;
            float4 bx = sbox[obj];
            float cx = (bx.x + bx.z) * 0.5f, cy = (bx.y + bx.w) * 0.5f;
            float w = bx.z - bx.x, h = bx.w - bx.y;
            float gx = (cx - pr.x) / (pr.z * 0.1f);
            float gy = (cy - pr.y) / (pr.w * 0.1f);
            float gw = __logf(w / pr.z) * 5.0f;
            float gh = __logf(h / pr.w) * 5.0f;
            float4 pl = ((const float4*)plocs)[(size_t)b * NP + p];
            locpart = fabsf(pl.x - gx) + fabsf(pl.y - gy) +
                      fabsf(pl.z - gw) + fabsf(pl.w - gh);
        }
        confneg[(size_t)b * NP + p] = isp ? 0.0f : conf;
    }

    for (int s = 32; s > 0; s >>= 1) {
        posconf += __shfl_xor(posconf, s, 64);
        locpart += __shfl_xor(locpart, s, 64);
        isp     += __shfl_xor(isp, s, 64);
    }
    __shared__ float w0[4], w1[4];
    __shared__ int wc[4];
    int wid = tid >> 6, lane = tid & 63;
    if (lane == 0) { w0[wid] = posconf; w1[wid] = locpart; wc[wid] = isp; }
    __syncthreads();
    if (tid == 0) {
        atomicAdd(&npos[b], wc[0] + wc[1] + wc[2] + wc[3]);
        atomicAdd(&accb[b * 3 + 0], (double)(w0[0] + w0[1] + w0[2] + w0[3]));
        atomicAdd(&accb[b * 3 + 1], (double)(w1[0] + w1[1] + w1[2] + w1[3]));
    }
}

// Exact top-k hard-negative sum (bit bisection, register-resident row) + last-block final.
__global__ __launch_bounds__(1024) void k_topk_final(const float* __restrict__ confneg,
                                                     const int* __restrict__ npos,
                                                     double* __restrict__ accb,
                                                     int* __restrict__ flag,
                                                     float* __restrict__ out) {
    __shared__ int   si[2][16];   // double-buffered by bit parity -> 1 barrier/step
    __shared__ double sd[16];
    __shared__ int   slast;
    const int tid = threadIdx.x, b = blockIdx.x;
    const int lane = tid & 63, wid = tid >> 6;

    const float* src = confneg + (size_t)b * NP;
    float val[9];
#pragma unroll
    for (int j = 0; j < 9; ++j) {
        int i = tid + j * 1024;
        val[j] = (i < NP) ? src[i] : 0.0f;  // 0 never counts (cand > 0)
    }
    int k = npos[b] * 3;
    if (k > NP) k = NP;

    if (k > 0) {  // block-uniform
        unsigned T = 0;
        for (int bit = 30; bit >= 0; --bit) {
            unsigned cand = T | (1u << bit);
            int cnt = 0;
#pragma unroll
            for (int j = 0; j < 9; ++j)
                cnt += (__float_as_uint(val[j]) >= cand) ? 1 : 0;
            for (int s = 32; s > 0; s >>= 1) cnt += __shfl_xor(cnt, s, 64);
            if (lane == 0) si[bit & 1][wid] = cnt;
            __syncthreads();
            int tot = 0;
#pragma unroll
            for (int w = 0; w < 16; ++w) tot += si[bit & 1][w];  // LDS broadcast reads
            if (tot >= k) T = cand;  // uniform decision, no 2nd barrier (dbl-buffered)
        }
        int cgt = 0;
        double sgt = 0.0;
#pragma unroll
        for (int j = 0; j < 9; ++j) {
            unsigned u = __float_as_uint(val[j]);
            if (u > T) { cgt++; sgt += (double)val[j]; }
        }
        for (int s = 32; s > 0; s >>= 1) {
            cgt += __shfl_xor(cgt, s, 64);
            sgt += __shfl_xor(sgt, s, 64);
        }
        if (lane == 0) { si[0][wid] = cgt; sd[wid] = sgt; }
        __syncthreads();
        if (tid == 0) {
            int cg = 0; double sg = 0.0;
            for (int w = 0; w < 16; ++w) { cg += si[0][w]; sg += sd[w]; }
            accb[b * 3 + 2] = sg + (double)(k - cg) * (double)__uint_as_float(T);
        }
    }
    // accb[b*3+2] stays 0 (zeroed by k_obj) when k == 0.

    // last-block ticket
    __threadfence();
    if (tid == 0) slast = (atomicAdd(flag, 1) == NB - 1) ? 1 : 0;
    __syncthreads();
    if (slast) {
        __threadfence();
        double pc = 0, lc = 0, hn = 0, nn = 0;
        if (tid < NB) {
            pc = accb[tid * 3 + 0];
            lc = accb[tid * 3 + 1];
            hn = accb[tid * 3 + 2];
            nn = (double)npos[tid];
        }
        if (tid < 128) {
            for (int s = 32; s > 0; s >>= 1) {
                pc += __shfl_xor(pc, s, 64);
                lc += __shfl_xor(lc, s, 64);
                hn += __shfl_xor(hn, s, 64);
                nn += __shfl_xor(nn, s, 64);
            }
            if (lane == 0) { sd[wid * 4 + 0] = pc; sd[wid * 4 + 1] = lc;
                             sd[wid * 4 + 2] = hn; sd[wid * 4 + 3] = nn; }
        }
        __syncthreads();
        if (tid == 0) {
            double P  = sd[0] + sd[4];
            double L  = sd[1] + sd[5];
            double H  = sd[2] + sd[6];
            double NT = sd[3] + sd[7];
            out[0] = (float)((H + P) / NT + L / (NT * 4.0));
        }
    }
}

extern "C" void kernel_launch(void* const* d_in, const int* in_sizes, int n_in,
                              void* d_out, int out_size, void* d_ws, size_t ws_size,
                              hipStream_t stream) {
    const float* plocs  = (const float*)d_in[0];
    const float* scores = (const float*)d_in[1];
    const float* boxes  = (const float*)d_in[2];
    const int*   labels = (const int*)d_in[3];
    const float* priors = (const float*)d_in[4];
    float* out = (float*)d_out;

    char* ws = (char*)d_ws;
    unsigned long long* packed2 = (unsigned long long*)ws;
    int*    npos    = (int*)(ws + 262144);
    double* accb    = (double*)(ws + 262656);
    int*    flag    = (int*)(ws + 265728);
    float*  confneg = (float*)(ws + 265984);

    hipLaunchKernelGGL(k_obj, dim3(NCH, NB), dim3(256), 0, stream,
                       boxes, priors, packed2, npos, accb, flag);
    hipLaunchKernelGGL(k_loss, dim3((NP + 255) / 256, NB), dim3(256), 0, stream,
                       plocs, scores, boxes, labels, priors, packed2, confneg, npos, accb);
    hipLaunchKernelGGL(k_topk_final, dim3(NB), dim3(1024), 0, stream,
                       confneg, npos, accb, flag, out);
}